// Round 2
// baseline (1467.782 us; speedup 1.0000x reference)
//
#include <hip/hip_runtime.h>
#include <stdint.h>

#define V 256
#define H 256
#define CONDD 64
#define WIDTH 64
#define KSTEPS 5
#define RROWS 16
#define GWMAX 0.05f

// ---------------- PRNG: counter-based splitmix64 -> U[0,1) ----------------
// Reference uses jax threefry with fixed key(42); exact reproduction is
// impractical. The output is a mean over 32768 rows, so any iid U[0,1)
// stream matches within MC noise (~0.08 << 0.78 threshold).
__device__ __forceinline__ uint64_t splitmix64(uint64_t x) {
  x += 0x9E3779B97F4A7C15ULL;
  x = (x ^ (x >> 30)) * 0xBF58476D1CE4E5B9ULL;
  x = (x ^ (x >> 27)) * 0x94D049BB133111EBULL;
  return x ^ (x >> 31);
}
__device__ __forceinline__ float u01(uint64_t ctr) {
  return (float)(uint32_t)(splitmix64(ctr) >> 40) * (1.0f / 16777216.0f);
}
__device__ __forceinline__ float sigmoidf(float x) { return 1.0f / (1.0f + expf(-x)); }
__device__ __forceinline__ float softplusf(float x) {
  return fmaxf(x, 0.0f) + log1pf(expf(-fabsf(x)));
}

// ---------------- prep kernels (run each call; d_ws is re-poisoned) -------
__global__ void k_prep_wt(const float* __restrict__ W, float* __restrict__ WT) {
  int h = blockIdx.x, v = threadIdx.x;
  WT[(size_t)h * V + v] = W[(size_t)v * H + h];
}
__global__ void k_prep_fc2t(const float* __restrict__ fc2_w, float* __restrict__ fc2T) {
  int idx = blockIdx.x * 256 + threadIdx.x;  // 0..98303
  int k = idx / 1536, o = idx % 1536;
  fc2T[idx] = fc2_w[(size_t)o * WIDTH + k];
}
__global__ void k_prep_wsum(const float* __restrict__ W, float* __restrict__ Wsum,
                            float* __restrict__ out) {
  int h = threadIdx.x;
  float s = 0.f;
  for (int v = 0; v < V; ++v) s += W[(size_t)v * H + h];
  Wsum[h] = s;
  if (h == 0) out[0] = 0.0f;  // d_out is poisoned 0xAA before every launch
}

// ---------------- activation-tile x weight matmul -------------------------
// acc[r] = sum_p vm[r][p] * M[p*256 + t]   (M reads coalesced across t,
// vm reads are uniform-address LDS broadcasts, float4-vectorized)
__device__ __forceinline__ void matmul16(const float (*vm)[V], const float* __restrict__ M,
                                         int t, float* acc) {
#pragma unroll
  for (int r = 0; r < RROWS; ++r) acc[r] = 0.0f;
  for (int p = 0; p < V; p += 4) {
    float m0 = M[(size_t)(p + 0) * H + t];
    float m1 = M[(size_t)(p + 1) * H + t];
    float m2 = M[(size_t)(p + 2) * H + t];
    float m3 = M[(size_t)(p + 3) * H + t];
#pragma unroll
    for (int r = 0; r < RROWS; ++r) {
      const float4 v4 = *reinterpret_cast<const float4*>(&vm[r][p]);
      acc[r] = fmaf(v4.x, m0, acc[r]);
      acc[r] = fmaf(v4.y, m1, acc[r]);
      acc[r] = fmaf(v4.z, m2, acc[r]);
      acc[r] = fmaf(v4.w, m3, acc[r]);
    }
  }
}

// ---------------- fused main kernel ---------------------------------------
__global__ __launch_bounds__(256) void rbm_fused(
    const float* __restrict__ v_data, const float* __restrict__ cond,
    const float* __restrict__ W, const float* __restrict__ bvec,
    const float* __restrict__ cvec, const float* __restrict__ fc1_w,
    const float* __restrict__ fc1_b, const float* __restrict__ fc2_b,
    const float* __restrict__ WT, const float* __restrict__ fc2T,
    const float* __restrict__ Wsum, float* __restrict__ out, int Btot, int nnoise) {
  const int t = threadIdx.x;          // 0..255 : doubles as h-index and v-index
  const int row0 = blockIdx.x * RROWS;

  __shared__ float conds[RROWS][CONDD];
  __shared__ float xs[RROWS][WIDTH];
  __shared__ float vdf[RROWS][V];   // v_data (0/1 floats)
  __shared__ float vmf[RROWS][V];   // v_model
  __shared__ float hw[RROWS][H];    // h * w_scale
  __shared__ float red[RROWS][8];
  __shared__ float blocksum;

  if (t < RROWS * 8) ((float*)red)[t] = 0.0f;
  if (t == 0) blocksum = 0.0f;

  // load cond rows
  for (int idx = t; idx < RROWS * CONDD; idx += 256) {
    int r = idx >> 6, k = idx & 63;
    conds[r][k] = cond[(size_t)(row0 + r) * CONDD + k];
  }
  // load v_data; init v_model (first nnoise rows replaced by Bernoulli(0.5))
  for (int idx = t; idx < RROWS * V; idx += 256) {
    int r = idx >> 8, col = idx & 255;
    int grow = row0 + r;
    float dv = v_data[(size_t)grow * V + col];
    float mv = dv;
    if (grow < nnoise) mv = (u01((uint64_t)grow * 256u + (uint32_t)col) < 0.5f) ? 1.0f : 0.0f;
    vdf[r][col] = dv;
    vmf[r][col] = mv;
  }
  __syncthreads();

  // x = tanh(cond @ fc1_w^T + fc1_b)
  for (int idx = t; idx < RROWS * WIDTH; idx += 256) {
    int r = idx >> 6, j = idx & 63;
    float s = fc1_b[j];
    for (int k = 0; k < CONDD; ++k) s = fmaf(conds[r][k], fc1_w[j * CONDD + k], s);
    xs[r][j] = tanhf(s);
  }
  __syncthreads();

  // conditional params: thread t owns h=t (c_mod, w_scale) and v=t (b_mod)
  float sgb[RROWS], sbb[RROWS], sgc[RROWS], sbc[RROWS], sgw[RROWS];
#pragma unroll
  for (int r = 0; r < RROWS; ++r) { sgb[r] = sbb[r] = sgc[r] = sbc[r] = sgw[r] = 0.0f; }
  for (int k = 0; k < WIDTH; ++k) {
    const float* col = fc2T + (size_t)k * 1536;  // coalesced across t
    float w0 = col[t], w1 = col[256 + t], w2 = col[512 + t], w3 = col[768 + t],
          w4 = col[1024 + t];
#pragma unroll
    for (int r = 0; r < RROWS; ++r) {
      float xv = xs[r][k];
      sgb[r] = fmaf(xv, w0, sgb[r]);
      sbb[r] = fmaf(xv, w1, sbb[r]);
      sgc[r] = fmaf(xv, w2, sgc[r]);
      sbc[r] = fmaf(xv, w3, sbc[r]);
      sgw[r] = fmaf(xv, w4, sgw[r]);
    }
  }
  float bm[RROWS], cm[RROWS], wsc[RROWS];
  {
    float fb0 = fc2_b[t], fb1 = fc2_b[256 + t], fb2 = fc2_b[512 + t],
          fb3 = fc2_b[768 + t], fb4 = fc2_b[1024 + t];
    float btv = bvec[t], ctv = cvec[t];
#pragma unroll
    for (int r = 0; r < RROWS; ++r) {
      bm[r] = fmaf(1.0f + (sgb[r] + fb0), btv, sbb[r] + fb1);
      cm[r] = fmaf(1.0f + (sgc[r] + fb2), ctv, sbc[r] + fb3);
      wsc[r] = 1.0f + GWMAX * tanhf(sgw[r] + fb4);
    }
  }
  __syncthreads();

  // ---------------- Gibbs chain (5 steps) ----------------
  float acc[RROWS];
  for (int step = 0; step < KSTEPS; ++step) {
    matmul16(vmf, W, t, acc);  // (v @ W)[h=t]
#pragma unroll
    for (int r = 0; r < RROWS; ++r) {
      float p = sigmoidf(fmaf(acc[r], wsc[r], cm[r]));
      uint64_t ctr = ((uint64_t)(1 + 2 * step) << 32) |
                     ((uint64_t)(uint32_t)(row0 + r) << 8) | (uint64_t)t;
      hw[r][t] = (u01(ctr) < p) ? wsc[r] : 0.0f;  // h * w_scale
    }
    __syncthreads();
    matmul16(hw, WT, t, acc);  // ((h*ws) @ W^T)[v=t]
#pragma unroll
    for (int r = 0; r < RROWS; ++r) {
      float p = sigmoidf(acc[r] + bm[r]);
      uint64_t ctr = ((uint64_t)(2 + 2 * step) << 32) |
                     ((uint64_t)(uint32_t)(row0 + r) << 8) | (uint64_t)t;
      vmf[r][t] = (u01(ctr) < p) ? 1.0f : 0.0f;
    }
    __syncthreads();
  }

  // ---------------- free energy: data pass then model pass ----------------
  const float wst = Wsum[t];
  matmul16(vdf, W, t, acc);
#pragma unroll
  for (int r = 0; r < RROWS; ++r) {
    float vw = acc[r];
    float q0 = softplusf(fmaf(vw, wsc[r], cm[r]));          // softplus(lin_v)
    float q1 = softplusf(fmaf(wst - vw, wsc[r], cm[r]));    // softplus(lin_f)
    float q4 = vdf[r][t] * bm[r];                           // Σ v*b_mod partial
    float q6 = bm[r];                                       // Σ b_mod partial
#pragma unroll
    for (int off = 32; off > 0; off >>= 1) {
      q0 += __shfl_down(q0, off);
      q1 += __shfl_down(q1, off);
      q4 += __shfl_down(q4, off);
      q6 += __shfl_down(q6, off);
    }
    if ((t & 63) == 0) {
      atomicAdd(&red[r][0], q0);
      atomicAdd(&red[r][1], q1);
      atomicAdd(&red[r][4], q4);
      atomicAdd(&red[r][6], q6);
    }
  }
  matmul16(vmf, W, t, acc);
#pragma unroll
  for (int r = 0; r < RROWS; ++r) {
    float vw = acc[r];
    float q2 = softplusf(fmaf(vw, wsc[r], cm[r]));
    float q3 = softplusf(fmaf(wst - vw, wsc[r], cm[r]));
    float q5 = vmf[r][t] * bm[r];
#pragma unroll
    for (int off = 32; off > 0; off >>= 1) {
      q2 += __shfl_down(q2, off);
      q3 += __shfl_down(q3, off);
      q5 += __shfl_down(q5, off);
    }
    if ((t & 63) == 0) {
      atomicAdd(&red[r][2], q2);
      atomicAdd(&red[r][3], q3);
      atomicAdd(&red[r][5], q5);
    }
  }
  __syncthreads();

  if (t < RROWS) {
    float Sspv_d = red[t][0], Sspf_d = red[t][1];
    float Sspv_m = red[t][2], Sspf_m = red[t][3];
    float Svb_d = red[t][4], Svb_m = red[t][5], Sb = red[t][6];
    // -fe_v = Σ v*b_mod + t2v ; -fe_f = Σ(1-v)*b_mod + t2f ; fe = -lse(-fe_v,-fe_f)
    float a_d = Svb_d + Sspv_d, b_d = (Sb - Svb_d) + Sspf_d;
    float fe_d = -(fmaxf(a_d, b_d) + log1pf(expf(-fabsf(a_d - b_d))));
    float a_m = Svb_m + Sspv_m, b_m = (Sb - Svb_m) + Sspf_m;
    float fe_m = -(fmaxf(a_m, b_m) + log1pf(expf(-fabsf(a_m - b_m))));
    atomicAdd(&blocksum, fe_d - fe_m);
  }
  __syncthreads();
  if (t == 0) atomicAdd(out, blocksum * (1.0f / (float)Btot));
}

// ---------------- launch ---------------------------------------------------
extern "C" void kernel_launch(void* const* d_in, const int* in_sizes, int n_in,
                              void* d_out, int out_size, void* d_ws, size_t ws_size,
                              hipStream_t stream) {
  const float* v_data = (const float*)d_in[0];
  const float* cond = (const float*)d_in[1];
  const float* W = (const float*)d_in[2];
  const float* bvec = (const float*)d_in[3];
  const float* cvec = (const float*)d_in[4];
  const float* fc1_w = (const float*)d_in[5];
  const float* fc1_b = (const float*)d_in[6];
  const float* fc2_w = (const float*)d_in[7];
  const float* fc2_b = (const float*)d_in[8];
  float* out = (float*)d_out;

  int Btot = in_sizes[0] / V;                 // 32768
  int nnoise = (int)((double)Btot * 0.1);     // int(B*0.1) = 3276

  // ws layout (floats): WT[256*256] | fc2T[64*1536] | Wsum[256]  (~656 KB)
  float* WT = (float*)d_ws;
  float* fc2T = WT + V * H;
  float* Wsum = fc2T + WIDTH * 1536;

  k_prep_wt<<<H, V, 0, stream>>>(W, WT);
  k_prep_fc2t<<<(WIDTH * 1536) / 256, 256, 0, stream>>>(fc2_w, fc2T);
  k_prep_wsum<<<1, H, 0, stream>>>(W, Wsum, out);
  rbm_fused<<<Btot / RROWS, 256, 0, stream>>>(v_data, cond, W, bvec, cvec, fc1_w, fc1_b,
                                              fc2_b, WT, fc2T, Wsum, out, Btot, nnoise);
}

// Round 3
// 693.342 us; speedup vs baseline: 2.1170x; 2.1170x over previous
//
#include <hip/hip_runtime.h>
#include <stdint.h>

#define V 256
#define H 256
#define CONDD 64
#define WIDTH 64
#define KSTEPS 5
#define BR 64
#define GWMAX 0.05f
#define SW(r) (((r) & 7) << 4)

typedef __attribute__((ext_vector_type(8))) short s16x8;
typedef __attribute__((ext_vector_type(4))) float f32x4;

__device__ __forceinline__ uint64_t splitmix64(uint64_t x) {
  x += 0x9E3779B97F4A7C15ULL;
  x = (x ^ (x >> 30)) * 0xBF58476D1CE4E5B9ULL;
  x = (x ^ (x >> 27)) * 0x94D049BB133111EBULL;
  return x ^ (x >> 31);
}
__device__ __forceinline__ unsigned short f2bf(float f) {
  uint32_t u = __float_as_uint(f);
  return (unsigned short)((u + 0x7FFFu + ((u >> 16) & 1u)) >> 16);
}
__device__ __forceinline__ float bf2f(unsigned short s) {
  return __uint_as_float(((uint32_t)s) << 16);
}
__device__ __forceinline__ float lcg_u01(uint64_t& s) {
  s = s * 6364136223846793005ULL + 1442695040888963407ULL;
  return (float)(uint32_t)(s >> 40) * (1.0f / 16777216.0f);
}
__device__ __forceinline__ float softplusf(float x) {
  return fmaxf(x, 0.0f) + log1pf(expf(-fabsf(x)));
}

// ---------------- prep kernels ------------------------------------------
// Pack W into MFMA B-fragment order for 16x16x32 bf16:
// frag f=(ks*16+nt): lane l holds B[k=ks*32+(l>>4)*8+j][n=nt*16+(l&15)], j=0..7.
__global__ void k_pack_w(const float* __restrict__ W, unsigned short* __restrict__ Wp_hi,
                         unsigned short* __restrict__ Wp_lo, unsigned short* __restrict__ WTp_hi) {
  int idx = blockIdx.x * 256 + threadIdx.x;  // 65536
  int j = idx & 7, l = (idx >> 3) & 63, nt = (idx >> 9) & 15, ks = idx >> 13;
  int kk = ks * 32 + (l >> 4) * 8 + j;
  int n = nt * 16 + (l & 15);
  float wv = W[(size_t)kk * H + n];           // B = W (k=v, n=h)
  unsigned short hi = f2bf(wv);
  Wp_hi[idx] = hi;
  Wp_lo[idx] = f2bf(wv - bf2f(hi));
  WTp_hi[idx] = f2bf(W[(size_t)n * H + kk]);  // B = W^T (k=h, n=v)
}
__global__ void k_pack_fc2(const float* __restrict__ fc2_w, unsigned short* __restrict__ fc2p) {
  int idx = blockIdx.x * 256 + threadIdx.x;  // 2*80*64*8 = 81920
  int j = idx & 7, l = (idx >> 3) & 63;
  int f = idx >> 9;                  // 0..159
  int ks = f / 80, nt = f % 80;
  fc2p[idx] = f2bf(fc2_w[(size_t)(nt * 16 + (l & 15)) * WIDTH + ks * 32 + (l >> 4) * 8 + j]);
}
__global__ void k_prep_misc(const float* __restrict__ W, float* __restrict__ Wsum,
                            float* __restrict__ out) {
  int h = threadIdx.x;
  float s = 0.f;
  for (int v = 0; v < V; ++v) s += W[(size_t)v * H + h];
  Wsum[h] = s;
  if (h == 0) out[0] = 0.0f;
}

// ---------------- MFMA tile passes --------------------------------------
// wave w owns all 4 row-tiles and cols [w*32, w*32+32) (n-tiles 2w, 2w+1).
__device__ __forceinline__ void mm_pass_lds(const char* srcL, const unsigned short* __restrict__ Wp,
                                            int w, int lc, int lg, f32x4 acc[4][2]) {
#pragma unroll
  for (int ks = 0; ks < 8; ++ks) {
    s16x8 af[4];
#pragma unroll
    for (int rt = 0; rt < 4; ++rt) {
      int r = rt * 16 + lc;
      af[rt] = *(const s16x8*)(srcL + r * 512 + ((ks * 64 + lg * 16) ^ SW(r)));
    }
#pragma unroll
    for (int n = 0; n < 2; ++n) {
      int f = ks * 16 + 2 * w + n;
      s16x8 bf = *(const s16x8*)(Wp + ((size_t)f * 64 + lg * 16 + lc) * 8);
#pragma unroll
      for (int rt = 0; rt < 4; ++rt)
        acc[rt][n] = __builtin_amdgcn_mfma_f32_16x16x32_bf16(af[rt], bf, acc[rt][n], 0, 0, 0);
    }
  }
}
__device__ __forceinline__ void mm_pass_gA(const float* __restrict__ vsrc,
                                           const unsigned short* __restrict__ Wp,
                                           int w, int lc, int lg, f32x4 acc[4][2]) {
#pragma unroll
  for (int ks = 0; ks < 8; ++ks) {
    s16x8 af[4];
#pragma unroll
    for (int rt = 0; rt < 4; ++rt) {
      const float* p = vsrc + (size_t)(rt * 16 + lc) * 256 + ks * 32 + lg * 8;
      float4 x0 = *(const float4*)p;
      float4 x1 = *(const float4*)(p + 4);
      s16x8 a;
      a[0] = (short)f2bf(x0.x); a[1] = (short)f2bf(x0.y);
      a[2] = (short)f2bf(x0.z); a[3] = (short)f2bf(x0.w);
      a[4] = (short)f2bf(x1.x); a[5] = (short)f2bf(x1.y);
      a[6] = (short)f2bf(x1.z); a[7] = (short)f2bf(x1.w);
      af[rt] = a;
    }
#pragma unroll
    for (int n = 0; n < 2; ++n) {
      int f = ks * 16 + 2 * w + n;
      s16x8 bf = *(const s16x8*)(Wp + ((size_t)f * 64 + lg * 16 + lc) * 8);
#pragma unroll
      for (int rt = 0; rt < 4; ++rt)
        acc[rt][n] = __builtin_amdgcn_mfma_f32_16x16x32_bf16(af[rt], bf, acc[rt][n], 0, 0, 0);
    }
  }
}

// ---------------- fused main kernel --------------------------------------
__global__ __launch_bounds__(512) void rbm_mfma(
    const float* __restrict__ v_data, const float* __restrict__ cond,
    const float* __restrict__ bvec, const float* __restrict__ cvec,
    const float* __restrict__ fc1_w, const float* __restrict__ fc1_b,
    const float* __restrict__ fc2_b, const unsigned short* __restrict__ Wp_hi,
    const unsigned short* __restrict__ Wp_lo, const unsigned short* __restrict__ WTp_hi,
    const unsigned short* __restrict__ fc2p, const float* __restrict__ Wsum,
    float* __restrict__ out, int Btot, int nnoise) {
  const int tid = threadIdx.x;
  const int w = tid >> 6, l = tid & 63, lc = l & 15, lg = l >> 4;
  const int row0 = blockIdx.x * BR;

  __shared__ unsigned short vmL[BR * 256];  // v_model bf16, XOR-swizzled rows (512B)
  __shared__ unsigned short hwL[BR * 256];  // h*wsc bf16; early: cond f32 + x bf16 overlay
  __shared__ float red[BR][8];

  uint64_t rs = splitmix64(((uint64_t)(blockIdx.x * 512 + tid) << 1) | 1ULL);

  if (tid < BR * 8) ((float*)red)[tid] = 0.0f;

  float* condS = (float*)hwL;            // [64][68] f32 = 17408 B
  char* xS = (char*)hwL + 64 * 68 * 4;   // 64 rows x 128 B bf16, swizzled

  // ---- stage cond (coalesced)
#pragma unroll
  for (int s = 0; s < 8; ++s) {
    int e = s * 512 + tid, r = e >> 6, k = e & 63;
    condS[r * 68 + k] = cond[(size_t)(row0 + r) * CONDD + k];
  }
  // ---- stage v_model (bf16, swizzled; first nnoise rows = Bernoulli(0.5))
#pragma unroll
  for (int s = 0; s < 4; ++s) {
    int unit = s * 512 + tid;
    int r = unit >> 5, c0 = (unit & 31) * 8;
    int g = row0 + r;
    s16x8 pk;
    if (g < nnoise) {
      rs = rs * 6364136223846793005ULL + 1442695040888963407ULL;
      uint32_t bits = (uint32_t)(rs >> 32);
#pragma unroll
      for (int j = 0; j < 8; ++j) pk[j] = (short)(((bits >> j) & 1u) ? 0x3F80 : 0);
    } else {
      const float* src = v_data + (size_t)g * 256 + c0;
      float4 a = *(const float4*)src, b = *(const float4*)(src + 4);
      pk[0] = (short)f2bf(a.x); pk[1] = (short)f2bf(a.y);
      pk[2] = (short)f2bf(a.z); pk[3] = (short)f2bf(a.w);
      pk[4] = (short)f2bf(b.x); pk[5] = (short)f2bf(b.y);
      pk[6] = (short)f2bf(b.z); pk[7] = (short)f2bf(b.w);
    }
    *(s16x8*)((char*)vmL + r * 512 + ((c0 * 2) ^ SW(r))) = pk;
  }
  __syncthreads();

  // ---- fc1: x = tanh(cond @ fc1_w^T + fc1_b), bf16 into xS (A-frag layout)
  {
    int r = tid >> 3, j0 = (tid & 7) * 8;
    float a8[8];
#pragma unroll
    for (int j = 0; j < 8; ++j) a8[j] = fc1_b[j0 + j];
    for (int k = 0; k < CONDD; ++k) {
      float cv = condS[r * 68 + k];
#pragma unroll
      for (int j = 0; j < 8; ++j)
        a8[j] = fmaf(cv, fc1_w[(size_t)(j0 + j) * CONDD + k], a8[j]);
    }
    s16x8 xp;
#pragma unroll
    for (int j = 0; j < 8; ++j) xp[j] = (short)f2bf(tanhf(a8[j]));
    *(s16x8*)(xS + r * 128 + ((j0 * 2) ^ SW(r))) = xp;
  }
  __syncthreads();

  // ---- fc2 via MFMA: params bm/cm/wsc in D-layout registers
  float bm[4][2][4], cm[4][2][4], ws[4][2][4];
  {  // pass A: slices gb(0), bb(1)
    f32x4 acc[2][4][2];
#pragma unroll
    for (int s = 0; s < 2; ++s)
#pragma unroll
      for (int rt = 0; rt < 4; ++rt)
#pragma unroll
        for (int n = 0; n < 2; ++n) acc[s][rt][n] = (f32x4){0.f, 0.f, 0.f, 0.f};
#pragma unroll
    for (int ks = 0; ks < 2; ++ks) {
      s16x8 af[4];
#pragma unroll
      for (int rt = 0; rt < 4; ++rt) {
        int r = rt * 16 + lc;
        af[rt] = *(const s16x8*)(xS + r * 128 + (((ks * 32 + lg * 8) * 2) ^ SW(r)));
      }
#pragma unroll
      for (int s = 0; s < 2; ++s)
#pragma unroll
        for (int n = 0; n < 2; ++n) {
          int f = ks * 80 + s * 16 + 2 * w + n;
          s16x8 bf = *(const s16x8*)(fc2p + ((size_t)f * 64 + l) * 8);
#pragma unroll
          for (int rt = 0; rt < 4; ++rt)
            acc[s][rt][n] = __builtin_amdgcn_mfma_f32_16x16x32_bf16(af[rt], bf, acc[s][rt][n], 0, 0, 0);
        }
    }
#pragma unroll
    for (int n = 0; n < 2; ++n) {
      int col = w * 32 + n * 16 + lc;
      float fb0 = fc2_b[col], fb1 = fc2_b[V + col], bv = bvec[col];
#pragma unroll
      for (int rt = 0; rt < 4; ++rt)
#pragma unroll
        for (int i = 0; i < 4; ++i)
          bm[rt][n][i] = fmaf(1.0f + (acc[0][rt][n][i] + fb0), bv, acc[1][rt][n][i] + fb1);
    }
  }
  {  // pass B: slices gc(2), bc(3), gw(4)
    f32x4 acc[3][4][2];
#pragma unroll
    for (int s = 0; s < 3; ++s)
#pragma unroll
      for (int rt = 0; rt < 4; ++rt)
#pragma unroll
        for (int n = 0; n < 2; ++n) acc[s][rt][n] = (f32x4){0.f, 0.f, 0.f, 0.f};
#pragma unroll
    for (int ks = 0; ks < 2; ++ks) {
      s16x8 af[4];
#pragma unroll
      for (int rt = 0; rt < 4; ++rt) {
        int r = rt * 16 + lc;
        af[rt] = *(const s16x8*)(xS + r * 128 + (((ks * 32 + lg * 8) * 2) ^ SW(r)));
      }
#pragma unroll
      for (int s = 0; s < 3; ++s)
#pragma unroll
        for (int n = 0; n < 2; ++n) {
          int f = ks * 80 + (2 + s) * 16 + 2 * w + n;
          s16x8 bf = *(const s16x8*)(fc2p + ((size_t)f * 64 + l) * 8);
#pragma unroll
          for (int rt = 0; rt < 4; ++rt)
            acc[s][rt][n] = __builtin_amdgcn_mfma_f32_16x16x32_bf16(af[rt], bf, acc[s][rt][n], 0, 0, 0);
        }
    }
#pragma unroll
    for (int n = 0; n < 2; ++n) {
      int col = w * 32 + n * 16 + lc;
      float fb2 = fc2_b[2 * V + col], fb3 = fc2_b[2 * V + H + col], fb4 = fc2_b[2 * V + 2 * H + col];
      float cv = cvec[col];
#pragma unroll
      for (int rt = 0; rt < 4; ++rt)
#pragma unroll
        for (int i = 0; i < 4; ++i) {
          cm[rt][n][i] = fmaf(1.0f + (acc[0][rt][n][i] + fb2), cv, acc[1][rt][n][i] + fb3);
          ws[rt][n][i] = 1.0f + GWMAX * tanhf(acc[2][rt][n][i] + fb4);
        }
    }
  }
  // Sb = sum_v bm[r][v]
#pragma unroll
  for (int rt = 0; rt < 4; ++rt)
#pragma unroll
    for (int i = 0; i < 4; ++i) {
      float s = bm[rt][0][i] + bm[rt][1][i];
      s += __shfl_xor(s, 1); s += __shfl_xor(s, 2);
      s += __shfl_xor(s, 4); s += __shfl_xor(s, 8);
      if (lc == 0) atomicAdd(&red[rt * 16 + lg * 4 + i][6], s);
    }
  __syncthreads();  // x/cond reads done; hwL free for h-samples

  // ---- Gibbs chain
  for (int step = 0; step < KSTEPS; ++step) {
    f32x4 acc[4][2];
#pragma unroll
    for (int rt = 0; rt < 4; ++rt)
#pragma unroll
      for (int n = 0; n < 2; ++n) acc[rt][n] = (f32x4){0.f, 0.f, 0.f, 0.f};
    mm_pass_lds((const char*)vmL, Wp_hi, w, lc, lg, acc);
#pragma unroll
    for (int rt = 0; rt < 4; ++rt)
#pragma unroll
      for (int n = 0; n < 2; ++n)
#pragma unroll
        for (int i = 0; i < 4; ++i) {
          float act = fmaf(acc[rt][n][i], ws[rt][n][i], cm[rt][n][i]);
          float e = __expf(-act);
          float u = lcg_u01(rs);
          unsigned short hv = (fmaf(u, e, u) < 1.0f) ? f2bf(ws[rt][n][i]) : (unsigned short)0;
          int r = rt * 16 + lg * 4 + i, c = w * 32 + n * 16 + lc;
          *(unsigned short*)((char*)hwL + r * 512 + ((c * 2) ^ SW(r))) = hv;
        }
    __syncthreads();
#pragma unroll
    for (int rt = 0; rt < 4; ++rt)
#pragma unroll
      for (int n = 0; n < 2; ++n) acc[rt][n] = (f32x4){0.f, 0.f, 0.f, 0.f};
    mm_pass_lds((const char*)hwL, WTp_hi, w, lc, lg, acc);
#pragma unroll
    for (int rt = 0; rt < 4; ++rt)
#pragma unroll
      for (int n = 0; n < 2; ++n)
#pragma unroll
        for (int i = 0; i < 4; ++i) {
          float act = acc[rt][n][i] + bm[rt][n][i];
          float e = __expf(-act);
          float u = lcg_u01(rs);
          unsigned short vv = (fmaf(u, e, u) < 1.0f) ? (unsigned short)0x3F80 : (unsigned short)0;
          int r = rt * 16 + lg * 4 + i, c = w * 32 + n * 16 + lc;
          *(unsigned short*)((char*)vmL + r * 512 + ((c * 2) ^ SW(r))) = vv;
        }
    __syncthreads();
  }

  // ---- free energy (hi+lo W split for accuracy)
  {
    float ws2[2];
    ws2[0] = Wsum[w * 32 + lc];
    ws2[1] = Wsum[w * 32 + 16 + lc];
    f32x4 acc[4][2];

    // model pass
#pragma unroll
    for (int rt = 0; rt < 4; ++rt)
#pragma unroll
      for (int n = 0; n < 2; ++n) acc[rt][n] = (f32x4){0.f, 0.f, 0.f, 0.f};
    mm_pass_lds((const char*)vmL, Wp_hi, w, lc, lg, acc);
    mm_pass_lds((const char*)vmL, Wp_lo, w, lc, lg, acc);
#pragma unroll
    for (int rt = 0; rt < 4; ++rt)
#pragma unroll
      for (int i = 0; i < 4; ++i) {
        float sv = 0.f, sf = 0.f, st = 0.f;
        int r = rt * 16 + lg * 4 + i;
#pragma unroll
        for (int n = 0; n < 2; ++n) {
          float vw = acc[rt][n][i];
          sv += softplusf(fmaf(vw, ws[rt][n][i], cm[rt][n][i]));
          sf += softplusf(fmaf(ws2[n] - vw, ws[rt][n][i], cm[rt][n][i]));
          int c = w * 32 + n * 16 + lc;
          float xv = bf2f(*(const unsigned short*)((const char*)vmL + r * 512 + ((c * 2) ^ SW(r))));
          st = fmaf(xv, bm[rt][n][i], st);
        }
        sv += __shfl_xor(sv, 1); sv += __shfl_xor(sv, 2); sv += __shfl_xor(sv, 4); sv += __shfl_xor(sv, 8);
        sf += __shfl_xor(sf, 1); sf += __shfl_xor(sf, 2); sf += __shfl_xor(sf, 4); sf += __shfl_xor(sf, 8);
        st += __shfl_xor(st, 1); st += __shfl_xor(st, 2); st += __shfl_xor(st, 4); st += __shfl_xor(st, 8);
        if (lc == 0) {
          atomicAdd(&red[r][3], sv);
          atomicAdd(&red[r][4], sf);
          atomicAdd(&red[r][5], st);
        }
      }

    // data pass (A-frags straight from global v_data)
#pragma unroll
    for (int rt = 0; rt < 4; ++rt)
#pragma unroll
      for (int n = 0; n < 2; ++n) acc[rt][n] = (f32x4){0.f, 0.f, 0.f, 0.f};
    mm_pass_gA(v_data + (size_t)row0 * 256, Wp_hi, w, lc, lg, acc);
    mm_pass_gA(v_data + (size_t)row0 * 256, Wp_lo, w, lc, lg, acc);
#pragma unroll
    for (int rt = 0; rt < 4; ++rt)
#pragma unroll
      for (int i = 0; i < 4; ++i) {
        float sv = 0.f, sf = 0.f, st = 0.f;
        int r = rt * 16 + lg * 4 + i;
#pragma unroll
        for (int n = 0; n < 2; ++n) {
          float vw = acc[rt][n][i];
          sv += softplusf(fmaf(vw, ws[rt][n][i], cm[rt][n][i]));
          sf += softplusf(fmaf(ws2[n] - vw, ws[rt][n][i], cm[rt][n][i]));
          int c = w * 32 + n * 16 + lc;
          float xv = v_data[(size_t)(row0 + r) * 256 + c];
          st = fmaf(xv, bm[rt][n][i], st);
        }
        sv += __shfl_xor(sv, 1); sv += __shfl_xor(sv, 2); sv += __shfl_xor(sv, 4); sv += __shfl_xor(sv, 8);
        sf += __shfl_xor(sf, 1); sf += __shfl_xor(sf, 2); sf += __shfl_xor(sf, 4); sf += __shfl_xor(sf, 8);
        st += __shfl_xor(st, 1); st += __shfl_xor(st, 2); st += __shfl_xor(st, 4); st += __shfl_xor(st, 8);
        if (lc == 0) {
          atomicAdd(&red[r][0], sv);
          atomicAdd(&red[r][1], sf);
          atomicAdd(&red[r][2], st);
        }
      }
  }
  __syncthreads();

  if (tid < 64) {
    int r = tid;
    float a_d = red[r][2] + red[r][0];
    float b_d = (red[r][6] - red[r][2]) + red[r][1];
    float fe_d = -(fmaxf(a_d, b_d) + log1pf(expf(-fabsf(a_d - b_d))));
    float a_m = red[r][5] + red[r][3];
    float b_m = (red[r][6] - red[r][5]) + red[r][4];
    float fe_m = -(fmaxf(a_m, b_m) + log1pf(expf(-fabsf(a_m - b_m))));
    float d = fe_d - fe_m;
#pragma unroll
    for (int m = 1; m < 64; m <<= 1) d += __shfl_xor(d, m);
    if (tid == 0) atomicAdd(out, d * (1.0f / (float)Btot));
  }
}

// ---------------- launch --------------------------------------------------
extern "C" void kernel_launch(void* const* d_in, const int* in_sizes, int n_in,
                              void* d_out, int out_size, void* d_ws, size_t ws_size,
                              hipStream_t stream) {
  const float* v_data = (const float*)d_in[0];
  const float* cond = (const float*)d_in[1];
  const float* W = (const float*)d_in[2];
  const float* bvec = (const float*)d_in[3];
  const float* cvec = (const float*)d_in[4];
  const float* fc1_w = (const float*)d_in[5];
  const float* fc1_b = (const float*)d_in[6];
  const float* fc2_w = (const float*)d_in[7];
  const float* fc2_b = (const float*)d_in[8];
  float* out = (float*)d_out;

  int Btot = in_sizes[0] / V;              // 32768
  int nnoise = (int)((double)Btot * 0.1);  // 3276

  // ws (shorts): Wp_hi[65536] | Wp_lo[65536] | WTp_hi[65536] | fc2p[81920] | Wsum f32[256]
  unsigned short* Wp_hi = (unsigned short*)d_ws;
  unsigned short* Wp_lo = Wp_hi + 65536;
  unsigned short* WTp_hi = Wp_lo + 65536;
  unsigned short* fc2p = WTp_hi + 65536;
  float* Wsum = (float*)(fc2p + 81920);

  k_pack_w<<<256, 256, 0, stream>>>(W, Wp_hi, Wp_lo, WTp_hi);
  k_pack_fc2<<<320, 256, 0, stream>>>(fc2_w, fc2p);
  k_prep_misc<<<1, 256, 0, stream>>>(W, Wsum, out);
  rbm_mfma<<<Btot / BR, 512, 0, stream>>>(v_data, cond, bvec, cvec, fc1_w, fc1_b, fc2_b,
                                          Wp_hi, Wp_lo, WTp_hi, fc2p, Wsum, out, Btot, nnoise);
}